// Round 8
// baseline (632.840 us; speedup 1.0000x reference)
//
#include <hip/hip_runtime.h>

// ConvMlp4d: conv4d(64->128) + bias + relu -> conv4d(128->64) + bias.
// R8: NO LDS, NO barriers. The chunk-planar activation layout
//   [nb][tu][v][chunk=c/8][w][c%8]
// makes MFMA A-fragments directly vector-loadable from global (lane l31 reads
// 16B at [v][ksg*2+hl][l31+kw-1] -> contiguous 512B wave run) through L1.
// B weights stream from L2 in frag-contiguous [tap][k16][O][16] layout.
// Halo: w edges per-lane clamp+zero-select; v edges wave-uniform select;
// t/u via block-uniform stage skip. Waves free-run (no sync -> no R6 race).
//   ws: x_t bf16 [2][65536][64] | h_t bf16 [2][65536][128] (chunk-planar)
//       w1t bf16 [81][4][128][16] | w2t bf16 [81][8][64][16]

using bf16x8 = __attribute__((ext_vector_type(8))) __bf16;
using f32x16 = __attribute__((ext_vector_type(16))) float;
using f32x4  = __attribute__((ext_vector_type(4))) float;

// ------- prep: x (2,64,65536) f32 -> x_t chunk-planar bf16 -------------------------
__global__ __launch_bounds__(256) void cvt_x(const float* __restrict__ x,
                                             __bf16* __restrict__ x_t) {
    __shared__ float lt[64][65];
    const int nb = blockIdx.y;
    const int p0 = blockIdx.x * 64;
    const int tu = p0 >> 10;
    const float* src = x + (size_t)nb * 64 * 65536;
    __bf16* dst = x_t + (size_t)nb * 65536 * 64;
    #pragma unroll
    for (int i = 0; i < 16; ++i) {
        int idx = i * 256 + threadIdx.x;
        int c = idx >> 6, p = idx & 63;
        lt[c][p] = src[(size_t)c * 65536 + p0 + p];
    }
    __syncthreads();
    #pragma unroll
    for (int i = 0; i < 16; ++i) {
        int idx = i * 256 + threadIdx.x;
        int c = idx >> 6, pl = idx & 63;
        int p = p0 + pl;
        int v = (p >> 5) & 31, w = p & 31;
        dst[(size_t)(tu * 32 + v) * 2048 + (c >> 3) * 256 + w * 8 + (c & 7)] =
            (__bf16)lt[c][pl];
    }
}

// ------- prep: w (O,CIN,81) f32 -> wt [81][CIN/16][COUT][16] bf16 ------------------
// Block per tap: coalesced 2B writes, gather reads (L2-cached, weights ~2.7MB).
template <int CIN>
__global__ __launch_bounds__(256) void cvt_w(const float* __restrict__ w,
                                             __bf16* __restrict__ wt) {
    constexpr int COUT = 8192 / CIN;
    constexpr int LOGC = (CIN == 64) ? 7 : 6;   // log2(COUT)
    const int tap = blockIdx.x;                 // 0..80
    __bf16* dst = wt + (size_t)tap * 8192;
    #pragma unroll
    for (int it = 0; it < 32; ++it) {
        const int i  = it * 256 + threadIdx.x;  // kg*(COUT*16) + o*16 + cl
        const int cl = i & 15;
        const int o  = (i >> 4) & (COUT - 1);
        const int kg = i >> (4 + LOGC);
        dst[i] = (__bf16)w[(size_t)(o * CIN + kg * 16 + cl) * 81 + tap];
    }
}

// ---------------- fused conv4d (direct-load implicit GEMM, 32x32x16 bf16) ----------
// Block 256 thr = 4 waves arranged WM x WN. Wave tile: M=64 (2 acc rows), N=NT*32.
// Block tile: M = WM*64 (v-span WM*2), N = WN*NT*32. No LDS.
template <int CIN, int COUT, int WM, int WN, int NT, bool RELU>
__global__ __launch_bounds__(256, 3) void conv4d_mfma(
    const __bf16* __restrict__ in_t,   // chunk-planar activations
    const __bf16* __restrict__ wt,     // [81][CIN/16][COUT][16]
    const float* __restrict__ bias,    // [COUT]
    __bf16* __restrict__ out_bf,       // chunk-planar (RELU path)
    float* __restrict__ out_f)         // [2][COUT][65536]  (else)
{
    constexpr int KST   = CIN / 16;
    constexpr int VSPAN = WM * 2;
    constexpr int VGB   = (VSPAN == 4) ? 3 : 2;

    const int tid  = threadIdx.x;
    const int lane = tid & 63;
    const int l31  = lane & 31;
    const int hl   = lane >> 5;
    const int wv   = tid >> 6;
    const int gmi  = (WN == 2) ? (wv >> 1) : wv;
    const int gni  = (WN == 2) ? (wv & 1) : 0;

    // grid: xcd(3b) | ulo(1b) | vg(VGB) | t(2b) | nb(1b); u = xcd*2+ulo
    const int bid = blockIdx.x;
    const int xcd = bid & 7;
    const int s0  = bid >> 3;
    const int u   = xcd * 2 + (s0 & 1);
    const int vg  = (s0 >> 1) & ((1 << VGB) - 1);
    const int t   = (s0 >> (1 + VGB)) & 3;
    const int nb  = (s0 >> (3 + VGB)) & 1;
    const int v0  = vg * VSPAN;
    const int pbase = ((t * 16 + u) * 32 + v0) * 32;

    const __bf16* inb = in_t + (size_t)nb * 65536 * CIN;

    // per-lane w offsets + validity (elements); chunk sel via hl
    int  wloff[3];
    bool wok[3];
    #pragma unroll
    for (int kw = 0; kw < 3; ++kw) {
        const int w_in = l31 + kw - 1;
        wok[kw]   = (unsigned)w_in < 32u;
        wloff[kw] = hl * 256 + w_in * 8;
    }
    // wave-uniform v offsets + validity for this wave's 4 A rows
    int  voff[4];
    bool vok[4];
    #pragma unroll
    for (int r = 0; r < 4; ++r) {
        const int v_in = v0 - 1 + gmi * 2 + r;
        vok[r]  = (unsigned)v_in < 32u;
        voff[r] = v_in * (CIN * 32);
    }

    // B lane pointers: o = (gni*NT+nt)*32 + l31; + hl*8 within 16-ch group
    const __bf16* wlane[NT];
    #pragma unroll
    for (int nt = 0; nt < NT; ++nt)
        wlane[nt] = wt + ((gni * NT + nt) * 32 + l31) * 16 + hl * 8;

    // valid (kt,ku) stage list (block-uniform)
    int sb[9], tb0[9], nst = 0;
    #pragma unroll
    for (int kt = 0; kt < 3; ++kt) {
        const int t_in = t + kt - 1;
        if ((unsigned)t_in >= 4u) continue;
        #pragma unroll
        for (int ku = 0; ku < 3; ++ku) {
            const int u_in = u + ku - 1;
            if ((unsigned)u_in >= 16u) continue;
            sb[nst]  = (t_in * 16 + u_in) * 1024 * CIN;
            tb0[nst] = (kt * 3 + ku) * 9;
            ++nst;
        }
    }

    bf16x8 zf;
    #pragma unroll
    for (int j = 0; j < 8; ++j) zf[j] = (__bf16)0.f;

    f32x16 acc[2][NT];
    #pragma unroll
    for (int mt = 0; mt < 2; ++mt)
        #pragma unroll
        for (int nt = 0; nt < NT; ++nt)
            #pragma unroll
            for (int i = 0; i < 16; ++i)
                acc[mt][nt][i] = 0.f;

    #pragma unroll 1
    for (int st = 0; st < nst; ++st) {
        const __bf16* ibase = inb + sb[st];
        const int tapb = tb0[st];
        #pragma unroll 2
        for (int ksg = 0; ksg < KST; ++ksg) {
            const __bf16* kbase = ibase + ksg * 512;
            #pragma unroll
            for (int kw = 0; kw < 3; ++kw) {
                bf16x8 af[4];
                #pragma unroll
                for (int r = 0; r < 4; ++r) {
                    const bool ok = vok[r] && wok[kw];
                    const int off = ok ? (voff[r] + wloff[kw]) : 0;
                    bf16x8 v = *(const bf16x8*)(kbase + off);
                    af[r] = ok ? v : zf;
                }
                bf16x8 bv[3][NT];
                #pragma unroll
                for (int kv = 0; kv < 3; ++kv) {
                    const int wo = ((tapb + kv * 3 + kw) * KST + ksg) * (COUT * 16);
                    #pragma unroll
                    for (int nt = 0; nt < NT; ++nt)
                        bv[kv][nt] = *(const bf16x8*)(wlane[nt] + wo);
                }
                #pragma unroll
                for (int kv = 0; kv < 3; ++kv)
                    #pragma unroll
                    for (int rr = 0; rr < 2; ++rr)
                        #pragma unroll
                        for (int nt = 0; nt < NT; ++nt)
                            acc[rr][nt] = __builtin_amdgcn_mfma_f32_32x32x16_bf16(
                                af[rr + kv], bv[kv][nt], acc[rr][nt], 0, 0, 0);
            }
        }
    }

    // ---- epilogue: C/D 32x32: col = lane&31, row = (reg&3) + 8*(reg>>2) + 4*hl ----
    #pragma unroll
    for (int nt = 0; nt < NT; ++nt) {
        const int o = (gni * NT + nt) * 32 + l31;
        const float bvls = bias[o];
        #pragma unroll
        for (int mt = 0; mt < 2; ++mt) {
            const int pb = pbase + (gmi * 2 + mt) * 32;
            if constexpr (RELU) {
                #pragma unroll
                for (int rg = 0; rg < 4; ++rg)
                    #pragma unroll
                    for (int j = 0; j < 4; ++j) {
                        float v = acc[mt][nt][rg * 4 + j] + bvls;
                        v = v > 0.f ? v : 0.f;
                        const int p = pb + j + 8 * rg + 4 * hl;
                        const int vv = (p >> 5) & 31, ww = p & 31, tu = p >> 10;
                        out_bf[(size_t)nb * 65536 * COUT +
                               (size_t)(tu * 32 + vv) * (32 * COUT) +
                               (o >> 3) * 256 + ww * 8 + (o & 7)] = (__bf16)v;
                    }
            } else {
                #pragma unroll
                for (int rg = 0; rg < 4; ++rg) {
                    f32x4 sv;
                    #pragma unroll
                    for (int j = 0; j < 4; ++j)
                        sv[j] = acc[mt][nt][rg * 4 + j] + bvls;
                    const int p = pb + 8 * rg + 4 * hl;
                    *(f32x4*)(out_f + ((size_t)nb * COUT + o) * 65536 + p) = sv;
                }
            }
        }
    }
}

extern "C" void kernel_launch(void* const* d_in, const int* in_sizes, int n_in,
                              void* d_out, int out_size, void* d_ws, size_t ws_size,
                              hipStream_t stream) {
    const float* x  = (const float*)d_in[0];
    const float* w1 = (const float*)d_in[1];
    const float* b1 = (const float*)d_in[2];
    const float* w2 = (const float*)d_in[3];
    const float* b2 = (const float*)d_in[4];
    float* out = (float*)d_out;

    char* ws = (char*)d_ws;
    __bf16* x_t = (__bf16*)ws;                               // 16,777,216 B
    __bf16* h_t = (__bf16*)(ws + 16777216);                  // 33,554,432 B
    __bf16* w1t = (__bf16*)(ws + 50331648);                  //  1,327,104 B
    __bf16* w2t = (__bf16*)(ws + 51658752);                  //  1,327,104 B

    cvt_x<<<dim3(1024, 2), 256, 0, stream>>>(x, x_t);
    cvt_w<64><<<81, 256, 0, stream>>>(w1, w1t);
    cvt_w<128><<<81, 256, 0, stream>>>(w2, w2t);

    // conv1: waves 2m x 2n (NT=2, N=128), v-span 4, grid 1024, relu -> chunk-planar
    conv4d_mfma<64, 128, 2, 2, 2, true><<<1024, 256, 0, stream>>>(x_t, w1t, b1, h_t,
                                                                  nullptr);
    // conv2: waves 4m x 1n (NT=2, N=64), v-span 8, grid 512, fp32 planar out
    conv4d_mfma<128, 64, 4, 1, 2, false><<<512, 256, 0, stream>>>(h_t, w2t, b2,
                                                                  nullptr, out);
}

// Round 9
// 479.104 us; speedup vs baseline: 1.3209x; 1.3209x over previous
//
#include <hip/hip_runtime.h>

// ConvMlp4d: conv4d(64->128) + bias + relu -> conv4d(128->64) + bias.
// R9 = R7 with BARRIER-FREE per-wave staging: each wave DMAs its own private
// A-buffer (4 rows x 4 chunks x 34 wp = 8704 B; ping-pong 17408 B/wave,
// 69632 B/block). No __syncthreads in the K-loop; each wave gates on its own
// s_waitcnt vmcnt(0) (DMA issued one full unit earlier). Compute/weights/
// epilogue identical to R7. Cost: 2.7x A-DMA duplication (L2-resident),
// 2 blocks/CU.
//   ws: x_t bf16 [2][65536][64] | h_t bf16 [2][65536][128] (chunk-planar:
//       [nb][tu][v][chunk=c/8][w][c%8])
//       w1t bf16 [81][4][128][16] | w2t bf16 [81][8][64][16]

using bf16x8 = __attribute__((ext_vector_type(8))) __bf16;
using f32x16 = __attribute__((ext_vector_type(16))) float;
using f32x4  = __attribute__((ext_vector_type(4))) float;

typedef __attribute__((address_space(1))) const void as1_void;
typedef __attribute__((address_space(3))) void as3_void;
__device__ __forceinline__ void gload_lds16(const void* g, void* l) {
    __builtin_amdgcn_global_load_lds((as1_void*)g, (as3_void*)l, 16, 0, 0);
}

// ------- prep: x (2,64,65536) f32 -> x_t chunk-planar bf16 -------------------------
__global__ __launch_bounds__(256) void cvt_x(const float* __restrict__ x,
                                             __bf16* __restrict__ x_t) {
    __shared__ float lt[64][65];
    const int nb = blockIdx.y;
    const int p0 = blockIdx.x * 64;
    const int tu = p0 >> 10;
    const float* src = x + (size_t)nb * 64 * 65536;
    __bf16* dst = x_t + (size_t)nb * 65536 * 64;
    #pragma unroll
    for (int i = 0; i < 16; ++i) {
        int idx = i * 256 + threadIdx.x;
        int c = idx >> 6, p = idx & 63;
        lt[c][p] = src[(size_t)c * 65536 + p0 + p];
    }
    __syncthreads();
    #pragma unroll
    for (int i = 0; i < 16; ++i) {
        int idx = i * 256 + threadIdx.x;
        int c = idx >> 6, pl = idx & 63;
        int p = p0 + pl;
        int v = (p >> 5) & 31, w = p & 31;
        dst[(size_t)(tu * 32 + v) * 2048 + (c >> 3) * 256 + w * 8 + (c & 7)] =
            (__bf16)lt[c][pl];
    }
}

// ------- prep: w (O,CIN,81) f32 -> wt [81][CIN/16][COUT][16] bf16 ------------------
template <int CIN>
__global__ __launch_bounds__(256) void cvt_w(const float* __restrict__ w,
                                             __bf16* __restrict__ wt) {
    constexpr int COUT = 8192 / CIN;
    constexpr int LOGC = (CIN == 64) ? 7 : 6;   // log2(COUT)
    const int tap = blockIdx.x;                 // 0..80
    __bf16* dst = wt + (size_t)tap * 8192;
    #pragma unroll
    for (int it = 0; it < 32; ++it) {
        const int i  = it * 256 + threadIdx.x;  // kg*(COUT*16) + o*16 + cl
        const int cl = i & 15;
        const int o  = (i >> 4) & (COUT - 1);
        const int kg = i >> (4 + LOGC);
        dst[i] = (__bf16)w[(size_t)(o * CIN + kg * 16 + cl) * 81 + tap];
    }
}

// ---------------- fused conv4d (implicit GEMM, 32x32x16 bf16 MFMA) -----------------
// Block 256 thr = 4 waves (2m x 2n). Block tile M=128 (v-span 4), N=2*NT*32.
// Per-wave private staging unit: [row4][chunk4][wp34] x 16B = 8704 B;
// ping-pong 17408 B/wave; block LDS 69632 B. No barriers in the K-loop.
template <int CIN, int COUT, int NT, bool RELU>
__global__ __launch_bounds__(256, 2) void conv4d_mfma(
    const __bf16* __restrict__ in_t,   // chunk-planar activations
    const __bf16* __restrict__ wt,     // [81][CIN/16][COUT][16]
    const float* __restrict__ bias,    // [COUT]
    __bf16* __restrict__ out_bf,       // chunk-planar (RELU path)
    float* __restrict__ out_f)         // [2][COUT][65536]  (else)
{
    constexpr int KST   = CIN / 16;
    constexpr int UNITS = CIN / 32;
    constexpr int LOGU  = (UNITS == 2) ? 1 : 2;
    __shared__ __bf16 tile[4 * 1088 * 8];   // 4 waves x (2 x 544 slots) x 16B

    const int tid  = threadIdx.x;
    const int lane = tid & 63;
    const int l31  = lane & 31;
    const int hl   = lane >> 5;
    const int wv   = tid >> 6;
    const int gmi  = wv >> 1;          // m wave-row 0..1
    const int gni  = wv & 1;           // n wave-col 0..1

    // grid: xcd(3b) | ulo(1b) | vg(3b) | t(2b) | nb(1b); u = xcd*2+ulo -> 1024
    const int bid = blockIdx.x;
    const int xcd = bid & 7;
    const int s0  = bid >> 3;
    const int u   = xcd * 2 + (s0 & 1);
    const int vg  = (s0 >> 1) & 7;
    const int t   = (s0 >> 4) & 3;
    const int nb  = (s0 >> 6) & 1;
    const int v0  = vg * 4;
    const int pbase = ((t * 16 + u) * 32 + v0) * 32;

    const __bf16* inb = in_t + (size_t)nb * 65536 * CIN;

    // ---- per-wave staging offsets: 9 DMA rounds, slot = r*64 + lane (<544) ----
    // LDS slot layout per wave-buffer: [row4][chunk4][wp34]; global elem offset
    // within (plane,unit): v_in*(CIN*32) + chunk*256 + w_in*8
    int goff[9];
    #pragma unroll
    for (int r = 0; r < 9; ++r) {
        const int slot = r * 64 + lane;
        const int row  = slot / 136;
        const int rem  = slot - row * 136;
        const int chunk = rem / 34;
        const int wp   = rem - chunk * 34;
        const int v_in = v0 - 1 + gmi * 2 + row;
        const int w_in = wp - 1;
        const bool ok = (slot < 544) && ((unsigned)v_in < 32u) &&
                        ((unsigned)w_in < 32u);
        goff[r] = ok ? (v_in * (CIN * 32) + chunk * 256 + w_in * 8) : -1;
    }

    // ---- one-time zero pre-fill of invalid slots (both of MY buffers) ----
    char* mybuf = (char*)tile + wv * 17408;
    #pragma unroll
    for (int r = 0; r < 9; ++r) {
        const int slot = r * 64 + lane;
        if (slot < 544 && goff[r] < 0) {
            *(uint4*)(mybuf + slot * 16) = make_uint4(0u, 0u, 0u, 0u);
            *(uint4*)(mybuf + 8704 + slot * 16) = make_uint4(0u, 0u, 0u, 0u);
        }
    }
    asm volatile("s_waitcnt lgkmcnt(0)" ::: "memory");

    // A-read lane base (16B slots within my buffer): slot = row*136 + (ks*2+hl)*34
    //                                                      + l31 + kw
    const bf16x8* mybuf16 = (const bf16x8*)mybuf;
    const int lane_base = hl * 34 + l31;

    // B lane pointers: o = (gni*NT+nt)*32 + l31; + hl*8 within 16-ch group
    const __bf16* wlane[NT];
    #pragma unroll
    for (int nt = 0; nt < NT; ++nt)
        wlane[nt] = wt + ((gni * NT + nt) * 32 + l31) * 16 + hl * 8;

    // ---- valid (kt,ku) stage list (block-uniform) ----
    int sb[9], tb0[9], nst = 0;
    #pragma unroll
    for (int kt = 0; kt < 3; ++kt) {
        const int t_in = t + kt - 1;
        if ((unsigned)t_in >= 4u) continue;
        #pragma unroll
        for (int ku = 0; ku < 3; ++ku) {
            const int u_in = u + ku - 1;
            if ((unsigned)u_in >= 16u) continue;
            sb[nst]  = (t_in * 16 + u_in) * 1024 * CIN;
            tb0[nst] = (kt * 3 + ku) * 9;
            ++nst;
        }
    }
    const int U = nst * UNITS;

    f32x16 acc[2][NT];
    #pragma unroll
    for (int mt = 0; mt < 2; ++mt)
        #pragma unroll
        for (int nt = 0; nt < NT; ++nt)
            #pragma unroll
            for (int i = 0; i < 16; ++i)
                acc[mt][nt][i] = 0.f;

    // DMA issue for unit j into MY ping-pong buffer (exec-masked halo)
    auto issue = [&](int j) {
        const int st = j >> LOGU, ch = j & (UNITS - 1);
        const __bf16* gb = inb + sb[st] + ch * 1024;   // unit = 4 chunk-planes
        char* lb = mybuf + (j & 1) * 8704;
        #pragma unroll
        for (int r = 0; r < 9; ++r)
            if (goff[r] >= 0)
                gload_lds16(gb + goff[r], lb + r * 1024);
    };

    issue(0);
    #pragma unroll 1
    for (int i = 0; i < U; ++i) {
        // Own-wave drain only: DMA(i) was issued a full unit of compute ago.
        asm volatile("s_waitcnt vmcnt(0)" ::: "memory");
        if (i + 1 < U) issue(i + 1);

        const int st = i >> LOGU, ch = i & (UNITS - 1);
        const int tapb = tb0[st];
        const bf16x8* tb = mybuf16 + (i & 1) * 544 + lane_base;
        #pragma unroll
        for (int ks = 0; ks < 2; ++ks) {
            const int ksg = ch * 2 + ks;
            #pragma unroll
            for (int kw = 0; kw < 3; ++kw) {
                bf16x8 af[4];
                #pragma unroll
                for (int r = 0; r < 4; ++r)
                    af[r] = tb[r * 136 + ks * 68 + kw];
                bf16x8 bv[3][NT];
                #pragma unroll
                for (int kv = 0; kv < 3; ++kv) {
                    const int wo = ((tapb + kv * 3 + kw) * KST + ksg) * (COUT * 16);
                    #pragma unroll
                    for (int nt = 0; nt < NT; ++nt)
                        bv[kv][nt] = *(const bf16x8*)(wlane[nt] + wo);
                }
                #pragma unroll
                for (int kv = 0; kv < 3; ++kv)
                    #pragma unroll
                    for (int rr = 0; rr < 2; ++rr)
                        #pragma unroll
                        for (int nt = 0; nt < NT; ++nt)
                            acc[rr][nt] = __builtin_amdgcn_mfma_f32_32x32x16_bf16(
                                af[rr + kv], bv[kv][nt], acc[rr][nt], 0, 0, 0);
            }
        }
    }

    // ---- epilogue: C/D 32x32: col = lane&31, row = (reg&3) + 8*(reg>>2) + 4*hl ----
    #pragma unroll
    for (int nt = 0; nt < NT; ++nt) {
        const int o = (gni * NT + nt) * 32 + l31;
        const float bvls = bias[o];
        #pragma unroll
        for (int mt = 0; mt < 2; ++mt) {
            const int pb = pbase + (gmi * 2 + mt) * 32;
            if constexpr (RELU) {
                #pragma unroll
                for (int rg = 0; rg < 4; ++rg)
                    #pragma unroll
                    for (int j = 0; j < 4; ++j) {
                        float v = acc[mt][nt][rg * 4 + j] + bvls;
                        v = v > 0.f ? v : 0.f;
                        const int p = pb + j + 8 * rg + 4 * hl;
                        const int vv = (p >> 5) & 31, ww = p & 31, tu = p >> 10;
                        out_bf[(size_t)nb * 65536 * COUT +
                               (size_t)(tu * 32 + vv) * (32 * COUT) +
                               (o >> 3) * 256 + ww * 8 + (o & 7)] = (__bf16)v;
                    }
            } else {
                #pragma unroll
                for (int rg = 0; rg < 4; ++rg) {
                    f32x4 sv;
                    #pragma unroll
                    for (int j = 0; j < 4; ++j)
                        sv[j] = acc[mt][nt][rg * 4 + j] + bvls;
                    const int p = pb + 8 * rg + 4 * hl;
                    *(f32x4*)(out_f + ((size_t)nb * COUT + o) * 65536 + p) = sv;
                }
            }
        }
    }
}

extern "C" void kernel_launch(void* const* d_in, const int* in_sizes, int n_in,
                              void* d_out, int out_size, void* d_ws, size_t ws_size,
                              hipStream_t stream) {
    const float* x  = (const float*)d_in[0];
    const float* w1 = (const float*)d_in[1];
    const float* b1 = (const float*)d_in[2];
    const float* w2 = (const float*)d_in[3];
    const float* b2 = (const float*)d_in[4];
    float* out = (float*)d_out;

    char* ws = (char*)d_ws;
    __bf16* x_t = (__bf16*)ws;                               // 16,777,216 B
    __bf16* h_t = (__bf16*)(ws + 16777216);                  // 33,554,432 B
    __bf16* w1t = (__bf16*)(ws + 50331648);                  //  1,327,104 B
    __bf16* w2t = (__bf16*)(ws + 51658752);                  //  1,327,104 B

    cvt_x<<<dim3(1024, 2), 256, 0, stream>>>(x, x_t);
    cvt_w<64><<<81, 256, 0, stream>>>(w1, w1t);
    cvt_w<128><<<81, 256, 0, stream>>>(w2, w2t);

    // conv1: waves 2m x 2n (NT=2, N=128), v-span 4, relu -> chunk-planar
    conv4d_mfma<64, 128, 2, true><<<1024, 256, 0, stream>>>(x_t, w1t, b1, h_t,
                                                            nullptr);
    // conv2: waves 2m x 2n (NT=1, N=64), v-span 4, fp32 planar out
    conv4d_mfma<128, 64, 1, false><<<1024, 256, 0, stream>>>(h_t, w2t, b2, nullptr,
                                                             out);
}

// Round 10
// 396.996 us; speedup vs baseline: 1.5941x; 1.2068x over previous
//
#include <hip/hip_runtime.h>

// ConvMlp4d: conv4d(64->128) + bias + relu -> conv4d(128->64) + bias.
// R10 = R7 staging/barrier structure, wave tile reshaped 64x64 -> 128x32
// (rr=4 M-tiles via kv-reuse af[6], NT=1): B-traffic per MFMA halves
// 512->256 B, making MFMA the single dominant pipe (per-unit-per-CU:
// MFMA ~7000 cyc, B ~3456, LDS-A ~5184).
//   conv1: block M=128 (v-span 4), waves 1gmi x 4gni (N=128), LDS 26112, 3/CU
//   conv2: block M=256 (v-span 8), waves 2gmi x 2gni (N=64),  LDS 43520, 2/CU
//   ws: x_t bf16 [2][65536][64] | h_t bf16 [2][65536][128] (chunk-planar:
//       [nb][tu][v][chunk=c/8][w][c%8])
//       w1t bf16 [81][4][128][16] | w2t bf16 [81][8][64][16]

using bf16x8 = __attribute__((ext_vector_type(8))) __bf16;
using f32x16 = __attribute__((ext_vector_type(16))) float;
using f32x4  = __attribute__((ext_vector_type(4))) float;

typedef __attribute__((address_space(1))) const void as1_void;
typedef __attribute__((address_space(3))) void as3_void;
__device__ __forceinline__ void gload_lds16(const void* g, void* l) {
    __builtin_amdgcn_global_load_lds((as1_void*)g, (as3_void*)l, 16, 0, 0);
}

// ------- prep: x (2,64,65536) f32 -> x_t chunk-planar bf16 -------------------------
__global__ __launch_bounds__(256) void cvt_x(const float* __restrict__ x,
                                             __bf16* __restrict__ x_t) {
    __shared__ float lt[64][65];
    const int nb = blockIdx.y;
    const int p0 = blockIdx.x * 64;
    const int tu = p0 >> 10;
    const float* src = x + (size_t)nb * 64 * 65536;
    __bf16* dst = x_t + (size_t)nb * 65536 * 64;
    #pragma unroll
    for (int i = 0; i < 16; ++i) {
        int idx = i * 256 + threadIdx.x;
        int c = idx >> 6, p = idx & 63;
        lt[c][p] = src[(size_t)c * 65536 + p0 + p];
    }
    __syncthreads();
    #pragma unroll
    for (int i = 0; i < 16; ++i) {
        int idx = i * 256 + threadIdx.x;
        int c = idx >> 6, pl = idx & 63;
        int p = p0 + pl;
        int v = (p >> 5) & 31, w = p & 31;
        dst[(size_t)(tu * 32 + v) * 2048 + (c >> 3) * 256 + w * 8 + (c & 7)] =
            (__bf16)lt[c][pl];
    }
}

// ------- prep: w (O,CIN,81) f32 -> wt [81][CIN/16][COUT][16] bf16 ------------------
template <int CIN>
__global__ __launch_bounds__(256) void cvt_w(const float* __restrict__ w,
                                             __bf16* __restrict__ wt) {
    constexpr int COUT = 8192 / CIN;
    constexpr int LOGC = (CIN == 64) ? 7 : 6;   // log2(COUT)
    const int tap = blockIdx.x;                 // 0..80
    __bf16* dst = wt + (size_t)tap * 8192;
    #pragma unroll
    for (int it = 0; it < 32; ++it) {
        const int i  = it * 256 + threadIdx.x;  // kg*(COUT*16) + o*16 + cl
        const int cl = i & 15;
        const int o  = (i >> 4) & (COUT - 1);
        const int kg = i >> (4 + LOGC);
        dst[i] = (__bf16)w[(size_t)(o * CIN + kg * 16 + cl) * 81 + tap];
    }
}

// ---------------- fused conv4d (implicit GEMM, 32x32x16 bf16 MFMA) -----------------
// Block 256 thr = 4 waves (GM x GN). Wave tile M=128 (rr=4), N=32 (NT=1).
// Block tile M = GM*128 (v-span GM*4), N = GN*32.
// Staging unit = one (kt,ku) stage x 32 channels: LDS [ROWS][chunk4][wp34] x 16B,
// ROWS = VSPAN+2; ping-pong. K-loop: waitcnt+barrier; issue DMA(i+1); compute(i).
template <int CIN, int COUT, int GM, int GN, int WPEU, bool RELU>
__global__ __launch_bounds__(256, WPEU) void conv4d_mfma(
    const __bf16* __restrict__ in_t,   // chunk-planar activations
    const __bf16* __restrict__ wt,     // [81][CIN/16][COUT][16]
    const float* __restrict__ bias,    // [COUT]
    __bf16* __restrict__ out_bf,       // chunk-planar (RELU path)
    float* __restrict__ out_f)         // [2][COUT][65536]  (else)
{
    constexpr int KST   = CIN / 16;
    constexpr int UNITS = CIN / 32;
    constexpr int LOGU  = (UNITS == 2) ? 1 : 2;
    constexpr int VSPAN = GM * 4;
    constexpr int VGB   = (VSPAN == 4) ? 3 : 2;      // vg bits (32/VSPAN)
    constexpr int ROWS  = VSPAN + 2;
    constexpr int SLOTS = ROWS * 136;                // 16B slots per unit
    constexpr int RNDS  = (SLOTS + 255) / 256;       // DMA rounds per unit
    constexpr int BUFB  = SLOTS * 16;                // unit bytes

    __shared__ __bf16 tile[2 * SLOTS * 8];           // ping-pong

    const int tid  = threadIdx.x;
    const int lane = tid & 63;
    const int l31  = lane & 31;
    const int hl   = lane >> 5;
    const int wv   = tid >> 6;
    const int gmi  = (GM == 2) ? (wv >> 1) : 0;
    const int gni  = (GM == 2) ? (wv & 1) : wv;

    // grid: xcd(3b) | ulo(1b) | vg(VGB) | t(2b) | nb(1b); u = xcd*2+ulo
    const int bid = blockIdx.x;
    const int xcd = bid & 7;
    const int s0  = bid >> 3;
    const int u   = xcd * 2 + (s0 & 1);
    const int vg  = (s0 >> 1) & ((1 << VGB) - 1);
    const int t   = (s0 >> (1 + VGB)) & 3;
    const int nb  = (s0 >> (3 + VGB)) & 1;
    const int v0  = vg * VSPAN;
    const int pbase = ((t * 16 + u) * 32 + v0) * 32;

    const __bf16* inb = in_t + (size_t)nb * 65536 * CIN;

    // ---- per-lane staging offsets (slot = r*256 + tid), chunk-planar global ----
    int goff[RNDS];
    #pragma unroll
    for (int r = 0; r < RNDS; ++r) {
        const int slot = r * 256 + tid;            // 16B-chunk slot
        const int row  = slot / 136;               // LDS [ROWS][chunk4][wp34]
        const int rem  = slot - row * 136;
        const int chunk = rem / 34;
        const int wp   = rem - chunk * 34;
        const int v_in = v0 - 1 + row;
        const int w_in = wp - 1;
        const bool ok = (slot < SLOTS) && ((unsigned)v_in < 32u) &&
                        ((unsigned)w_in < 32u);
        goff[r] = ok ? (v_in * (CIN * 32) + chunk * 256 + w_in * 8) : -1;
    }

    // ---- one-time zero pre-fill of invalid slots (both buffers) ----
    #pragma unroll
    for (int r = 0; r < RNDS; ++r) {
        const int slot = r * 256 + tid;
        if (slot < SLOTS && goff[r] < 0) {
            *(uint4*)((char*)tile + slot * 16) = make_uint4(0u, 0u, 0u, 0u);
            *(uint4*)((char*)tile + BUFB + slot * 16) = make_uint4(0u, 0u, 0u, 0u);
        }
    }

    // A-read lane base (16B slots): slot = (gmi*4 + j)*136 + (ks*2+hl)*34 + l31 + kw
    const int lane_base = gmi * 4 * 136 + hl * 34 + l31;
    const bf16x8* tile16 = (const bf16x8*)tile;

    // B lane pointer: o = gni*32 + l31; + hl*8 within the 16-ch group
    const __bf16* wlane = wt + ((size_t)(gni * 32 + l31)) * 16 + hl * 8;

    // ---- valid (kt,ku) stage list (block-uniform) ----
    int sb[9], tb0[9], nst = 0;
    #pragma unroll
    for (int kt = 0; kt < 3; ++kt) {
        const int t_in = t + kt - 1;
        if ((unsigned)t_in >= 4u) continue;
        #pragma unroll
        for (int ku = 0; ku < 3; ++ku) {
            const int u_in = u + ku - 1;
            if ((unsigned)u_in >= 16u) continue;
            sb[nst]  = (t_in * 16 + u_in) * 1024 * CIN;
            tb0[nst] = (kt * 3 + ku) * 9;
            ++nst;
        }
    }
    const int U = nst * UNITS;

    f32x16 acc[4];
    #pragma unroll
    for (int mt = 0; mt < 4; ++mt)
        #pragma unroll
        for (int i = 0; i < 16; ++i)
            acc[mt][i] = 0.f;

    // DMA issue for unit j (exec-masked; halo slots pre-zeroed, never written)
    auto issue = [&](int j) {
        const int st = j >> LOGU, ch = j & (UNITS - 1);
        const __bf16* gb = inb + sb[st] + ch * 1024;   // unit = 4 chunk-planes
        char* lb = ((char*)tile) + (j & 1) * BUFB + wv * 1024;
        #pragma unroll
        for (int r = 0; r < RNDS; ++r)
            if (goff[r] >= 0)
                gload_lds16(gb + goff[r], lb + r * 4096);
    };

    issue(0);
    #pragma unroll 1
    for (int i = 0; i < U; ++i) {
        // Forced drain: DMA(i) was issued a full unit of compute ago (i>0).
        asm volatile("s_waitcnt vmcnt(0) lgkmcnt(0)" ::: "memory");
        __syncthreads();
        if (i + 1 < U) issue(i + 1);

        const int st = i >> LOGU, ch = i & (UNITS - 1);
        const int tapb = tb0[st];
        const bf16x8* tb = tile16 + (i & 1) * SLOTS + lane_base;
        #pragma unroll
        for (int ks = 0; ks < 2; ++ks) {
            const int ksg = ch * 2 + ks;
            #pragma unroll
            for (int kw = 0; kw < 3; ++kw) {
                bf16x8 af[6];
                #pragma unroll
                for (int j = 0; j < 6; ++j)
                    af[j] = tb[j * 136 + ks * 68 + kw];
                bf16x8 bv[3];
                #pragma unroll
                for (int kv = 0; kv < 3; ++kv) {
                    const int wo = ((tapb + kv * 3 + kw) * KST + ksg) * (COUT * 16);
                    bv[kv] = *(const bf16x8*)(wlane + wo);
                }
                #pragma unroll
                for (int kv = 0; kv < 3; ++kv)
                    #pragma unroll
                    for (int rr = 0; rr < 4; ++rr)
                        acc[rr] = __builtin_amdgcn_mfma_f32_32x32x16_bf16(
                            af[rr + kv], bv[kv], acc[rr], 0, 0, 0);
            }
        }
    }

    // ---- epilogue: C/D 32x32: col = lane&31, row = (reg&3) + 8*(reg>>2) + 4*hl ----
    {
        const int o = gni * 32 + l31;
        const float bvls = bias[o];
        #pragma unroll
        for (int rr = 0; rr < 4; ++rr) {
            const int pb = pbase + (gmi * 4 + rr) * 32;
            if constexpr (RELU) {
                #pragma unroll
                for (int rg = 0; rg < 4; ++rg)
                    #pragma unroll
                    for (int j = 0; j < 4; ++j) {
                        float v = acc[rr][rg * 4 + j] + bvls;
                        v = v > 0.f ? v : 0.f;
                        const int p = pb + j + 8 * rg + 4 * hl;
                        const int vv = (p >> 5) & 31, ww = p & 31, tu = p >> 10;
                        out_bf[(size_t)nb * 65536 * COUT +
                               (size_t)(tu * 32 + vv) * (32 * COUT) +
                               (o >> 3) * 256 + ww * 8 + (o & 7)] = (__bf16)v;
                    }
            } else {
                #pragma unroll
                for (int rg = 0; rg < 4; ++rg) {
                    f32x4 sv;
                    #pragma unroll
                    for (int j = 0; j < 4; ++j)
                        sv[j] = acc[rr][rg * 4 + j] + bvls;
                    const int p = pb + 8 * rg + 4 * hl;
                    *(f32x4*)(out_f + ((size_t)nb * COUT + o) * 65536 + p) = sv;
                }
            }
        }
    }
}

extern "C" void kernel_launch(void* const* d_in, const int* in_sizes, int n_in,
                              void* d_out, int out_size, void* d_ws, size_t ws_size,
                              hipStream_t stream) {
    const float* x  = (const float*)d_in[0];
    const float* w1 = (const float*)d_in[1];
    const float* b1 = (const float*)d_in[2];
    const float* w2 = (const float*)d_in[3];
    const float* b2 = (const float*)d_in[4];
    float* out = (float*)d_out;

    char* ws = (char*)d_ws;
    __bf16* x_t = (__bf16*)ws;                               // 16,777,216 B
    __bf16* h_t = (__bf16*)(ws + 16777216);                  // 33,554,432 B
    __bf16* w1t = (__bf16*)(ws + 50331648);                  //  1,327,104 B
    __bf16* w2t = (__bf16*)(ws + 51658752);                  //  1,327,104 B

    cvt_x<<<dim3(1024, 2), 256, 0, stream>>>(x, x_t);
    cvt_w<64><<<81, 256, 0, stream>>>(w1, w1t);
    cvt_w<128><<<81, 256, 0, stream>>>(w2, w2t);

    // conv1: block M=128 (v-span 4), waves 1x4 (N=128), grid 1024, 3 blocks/CU
    conv4d_mfma<64, 128, 1, 4, 3, true><<<1024, 256, 0, stream>>>(x_t, w1t, b1, h_t,
                                                                  nullptr);
    // conv2: block M=256 (v-span 8), waves 2x2 (N=64), grid 512, 2 blocks/CU
    conv4d_mfma<128, 64, 2, 2, 2, false><<<512, 256, 0, stream>>>(h_t, w2t, b2,
                                                                  nullptr, out);
}